// Round 6
// baseline (423.098 us; speedup 1.0000x reference)
//
#include <hip/hip_runtime.h>
#include <stdint.h>

typedef unsigned short u16;
typedef float f32x4 __attribute__((ext_vector_type(4)));
typedef float f32x16 __attribute__((ext_vector_type(16)));
typedef short bf16x8 __attribute__((ext_vector_type(8)));

// ---------- helpers ----------
static __device__ __forceinline__ u16 f2bf(float f) {
  union { float f; unsigned u; } a; a.f = f;
  unsigned r = a.u + 0x7fffu + ((a.u >> 16) & 1u);   // round-nearest-even
  return (u16)(r >> 16);
}

static __device__ __forceinline__ void gld16(const void* g, void* l) {
  __builtin_amdgcn_global_load_lds(
      (const __attribute__((address_space(1))) void*)(uintptr_t)g,
      (__attribute__((address_space(3))) void*)(uintptr_t)l,
      16, 0, 0);
}

// ---------- cast fp32 [rows][cols] -> bf16 [rows][ldd] ----------
__global__ __launch_bounds__(256) void cast_strided(
    const float* __restrict__ src, u16* __restrict__ dst,
    int rows, int cols, int ldd) {
  const size_t total = (size_t)rows * cols / 4;
  for (size_t i = (size_t)blockIdx.x * 256 + threadIdx.x; i < total;
       i += (size_t)gridDim.x * 256) {
    const size_t e = i * 4;
    const int r = (int)(e / cols);
    const int c = (int)(e % cols);
    float4 v = *(const float4*)(src + e);
    ushort4 o;
    o.x = f2bf(v.x); o.y = f2bf(v.y); o.z = f2bf(v.z); o.w = f2bf(v.w);
    *(ushort4*)(dst + (size_t)r * ldd + c) = o;
  }
}

// ---------- B [E=8][O=4096][R=16] * SCALING -> Waug[:, 4096:4224] bf16 ----------
__global__ __launch_bounds__(256) void cast_b2(
    const float* __restrict__ B, u16* __restrict__ Waug) {
  int i = blockIdx.x * 256 + threadIdx.x;
  if (i >= 4096 * 128) return;
  const int o = i >> 7;
  const int er = i & 127;
  const int e = er >> 4;
  const int r = er & 15;
  float v = B[((size_t)e * 4096 + o) * 16 + r] * 2.0f;   // SCALING = 32/16
  Waug[(size_t)o * 4224 + 4096 + er] = f2bf(v);
}

// ---------- fused: cast x -> Xaug base cols AND compute gate weights ----------
__global__ __launch_bounds__(256) void cast_x_gate(
    const float* __restrict__ x, const float* __restrict__ Wg,
    u16* __restrict__ Xaug, float* __restrict__ wsc) {
  const int lane = threadIdx.x & 63;
  const int wv = threadIdx.x >> 6;
  const int n = blockIdx.x * 4 + wv;
  const float4* x4 = (const float4*)(x + (size_t)n * 4096);
  const float4* g4 = (const float4*)Wg;                  // [8][1024] float4
  u16* xr = Xaug + (size_t)n * 4224;
  float acc[8] = {0, 0, 0, 0, 0, 0, 0, 0};
#pragma unroll
  for (int ii = 0; ii < 16; ++ii) {
    const int i = ii * 64 + lane;
    float4 xv = x4[i];
    ushort4 o;
    o.x = f2bf(xv.x); o.y = f2bf(xv.y); o.z = f2bf(xv.z); o.w = f2bf(xv.w);
    *(ushort4*)(xr + i * 4) = o;
#pragma unroll
    for (int e = 0; e < 8; ++e) {
      float4 w4 = g4[e * 1024 + i];
      acc[e] += xv.x * w4.x + xv.y * w4.y + xv.z * w4.z + xv.w * w4.w;
    }
  }
#pragma unroll
  for (int e = 0; e < 8; ++e) {
#pragma unroll
    for (int off = 32; off > 0; off >>= 1)
      acc[e] += __shfl_xor(acc[e], off);
  }
  int i1 = 0; float m1 = acc[0];
#pragma unroll
  for (int e = 1; e < 8; ++e) if (acc[e] > m1) { m1 = acc[e]; i1 = e; }
  int i2 = -1; float m2 = -3.4e38f;
#pragma unroll
  for (int e = 0; e < 8; ++e) if (e != i1 && acc[e] > m2) { m2 = acc[e]; i2 = e; }
  float w1 = 1.0f / (1.0f + expf(m2 - m1));   // p1/(p1+p2) after softmax+renorm
  float w2 = 1.0f - w1;
  if (lane < 8)
    wsc[(size_t)n * 8 + lane] = (lane == i1) ? w1 : ((lane == i2) ? w2 : 0.0f);
}

// ---------- LoRA down-proj, split-K x4 -> f32 partials in hp ----------
__global__ __launch_bounds__(256) void lora_down(
    const u16* __restrict__ Xa, const u16* __restrict__ A2,
    float* __restrict__ hp) {
  __shared__ u16 sA[128 * 64];
  __shared__ u16 sB[128 * 64];
  const int t = threadIdx.x;
  const int lane = t & 63;
  const int wr = t >> 7;
  const int wc = (t >> 6) & 1;
  const int l15 = lane & 15;
  const int lhi = lane >> 4;
  f32x4 acc[4][4] = {};

  const int brow = blockIdx.x * 128;
  const int kbase = blockIdx.y * 1024;
  const int srow = t >> 3;
  const int scol = (t & 7) * 8;
  const size_t a_src = (size_t)(brow + srow) * 4224 + scol + kbase;
  const size_t b_src = (size_t)srow * 4096 + scol + kbase;

  for (int k0 = 0; k0 < 1024; k0 += 64) {
#pragma unroll
    for (int c = 0; c < 4; ++c)
      gld16(Xa + a_src + (size_t)c * 32 * 4224 + k0,
            &sA[(c * 32 + srow) * 64 + scol]);
#pragma unroll
    for (int c = 0; c < 4; ++c)
      gld16(A2 + b_src + (size_t)c * 32 * 4096 + k0,
            &sB[(c * 32 + srow) * 64 + scol]);
    __syncthreads();
#pragma unroll
    for (int kk = 0; kk < 2; ++kk) {
      bf16x8 av[4], bv[4];
#pragma unroll
      for (int m = 0; m < 4; ++m)
        av[m] = *(const bf16x8*)&sA[(wr * 64 + m * 16 + l15) * 64 + kk * 32 + lhi * 8];
#pragma unroll
      for (int n = 0; n < 4; ++n)
        bv[n] = *(const bf16x8*)&sB[(wc * 64 + n * 16 + l15) * 64 + kk * 32 + lhi * 8];
#pragma unroll
      for (int m = 0; m < 4; ++m)
#pragma unroll
        for (int n = 0; n < 4; ++n)
          acc[m][n] = __builtin_amdgcn_mfma_f32_16x16x32_bf16(av[m], bv[n], acc[m][n], 0, 0, 0);
    }
    __syncthreads();
  }
  float* out = hp + (size_t)blockIdx.y * (8192 * 128);
#pragma unroll
  for (int m = 0; m < 4; ++m) {
    const int rbase = brow + wr * 64 + m * 16 + lhi * 4;
#pragma unroll
    for (int n = 0; n < 4; ++n) {
      const int col = wc * 64 + n * 16 + l15;   // 0..127
#pragma unroll
      for (int j = 0; j < 4; ++j)
        out[(size_t)(rbase + j) * 128 + col] = acc[m][n][j];
    }
  }
}

// ---------- reduce split-K partials, apply gate weight, store bf16 to Xaug ----------
__global__ __launch_bounds__(256) void reduce_hw(
    const float* __restrict__ hp, const float* __restrict__ wsc,
    u16* __restrict__ Xaug) {
  int i = blockIdx.x * 256 + threadIdx.x;
  if (i >= 8192 * 128) return;
  const int n = i >> 7;
  const int er = i & 127;
  const int e = er >> 4;
  float v = hp[i] + hp[i + 1048576] + hp[i + 2097152] + hp[i + 3145728];
  Xaug[(size_t)n * 4224 + 4096 + er] = f2bf(v * wsc[n * 8 + e]);
}

// ================== 256x256 main GEMM, 32x32x16 MFMA, pipelined reads ==================
// BM=BN=256, BK=64, 512 thr (8 waves 2x4), per-wave 128x64 out as 4x2 tiles of 32x32.
// LDS layout / staging / st_16x32 involution IDENTICAL to the verified r3-r5 kernel
// (2 bufs x (A 32KB + B 32KB), 1KB subtiles of 16 rows x 32 k, pre-swizzled global src).
// Frag addressing for 32x32x16: lane -> row r=lane&31, k0=(lane>>5)*8 (+kk*16);
//   byte = rowgrp<<11 + kgrp<<10 + [((r&15)<<6) + (khalf<<4) + (((kk&1)^sbit)<<5)]
//   with sbit=(r>>3)&1 (same involution as before, derivation checked vs staged content).
// C/D layout 32x32 (m74/m101): col=lane&31, row=(reg&3)+8*(reg>>2)+4*(lane>>5).
// Schedule = r5's: reads trail the previous MFMA cluster; 4 barriers/K-tile;
// counted vmcnt(4) per K-tile (0 only at tail); setprio around MFMA clusters.
#define BAR do { asm volatile("" ::: "memory"); __builtin_amdgcn_s_barrier(); asm volatile("" ::: "memory"); } while (0)

#define RDA32(BUF, MH)                                                           \
  { _Pragma("unroll") for (int m2 = 0; m2 < 2; ++m2)                             \
    _Pragma("unroll") for (int kk = 0; kk < 4; ++kk)                             \
      av[m2][kk] = *(const bf16x8*)(lds + (BUF) + fA + ((((MH) * 2 + m2)) << 12) \
                     + ((kk >> 1) << 10) + ((((kk & 1) ^ sbit)) << 5)); }

#define RDB32(BUF, NH)                                                           \
  { _Pragma("unroll") for (int kk = 0; kk < 4; ++kk)                             \
      bv[NH][kk] = *(const bf16x8*)(lds + (BUF) + fB + ((NH) << 12)              \
                     + ((kk >> 1) << 10) + ((((kk & 1) ^ sbit)) << 5)); }

#define MFMAQ32(MH, NH)                                                          \
  { __builtin_amdgcn_s_setprio(1);                                               \
    _Pragma("unroll") for (int kk = 0; kk < 4; ++kk)                             \
    _Pragma("unroll") for (int m2 = 0; m2 < 2; ++m2)                             \
      acc[(MH) * 2 + m2][NH] = __builtin_amdgcn_mfma_f32_32x32x16_bf16(          \
          av[m2][kk], bv[NH][kk], acc[(MH) * 2 + m2][NH], 0, 0, 0);              \
    __builtin_amdgcn_s_setprio(0); }

__global__ __launch_bounds__(512, 2) void gemm8p(
    const u16* __restrict__ Ag, const u16* __restrict__ Bg,
    const float* __restrict__ bias, float* __restrict__ C,
    int lda, int ldb, int ldc, int K) {
  __shared__ __align__(1024) char lds[131072];
  const int t = threadIdx.x;
  const int lane = t & 63;
  const int w = t >> 6;
  const int wr = w >> 2, wc = w & 3;

  // XCD-slab mapping: xcd owns tile_m in [xcd*4, xcd*4+4); concurrent 4-block
  // groups share one B-panel in L2; A-panels hit HBM exactly once.
  const int bid = blockIdx.x;
  const int g = bid >> 3;
  const int tile_m = (bid & 7) * 4 + (g & 3);
  const int tile_n = g >> 2;
  const int brow = tile_m << 8;
  const int bcol = tile_n << 8;

  // pre-swizzled per-lane source coords (st_16x32 involution)
  const int sb = (lane << 4) ^ (lane & 32);
  const int srow = sb >> 6;
  const int scol = (sb & 63) >> 1;

  // wave w stages A subtiles w*4..w*4+3 and B subtiles w*4..w*4+3 per K-tile
  const u16* pA[4]; const u16* pB[4];
#pragma unroll
  for (int s = 0; s < 4; ++s) {
    const int idx = w * 4 + s;
    const int rg = idx >> 1, cs = idx & 1;
    pA[s] = Ag + (size_t)(brow + rg * 16 + srow) * lda + cs * 32 + scol;
    pB[s] = Bg + (size_t)(bcol + rg * 16 + srow) * ldb + cs * 32 + scol;
  }
  const int ldsA = w << 12;
  const int ldsB = 32768 + (w << 12);

  // 32x32 fragment read bases
  const int r = lane & 31;            // A-row / B-col within 32-frag
  const int khalf = lane >> 5;        // k sub-half (8 elems = 16 B)
  const int sbit = (r >> 3) & 1;      // involution bit
  const int fin = ((r & 15) << 6) + (khalf << 4);
  const int fA = (wr << 14) + ((r >> 4) << 11) + fin;
  const int fB = 32768 + (wc << 13) + ((r >> 4) << 11) + fin;

  f32x16 acc[4][2] = {};
  bf16x8 av[2][4], bv[2][4];

  const int NT = K >> 6;   // 66 K-tiles

  // ---- prologue: stage A(0)->buf0, B(0)->buf0, B(1)->buf1 ----
#pragma unroll
  for (int s = 0; s < 4; ++s) gld16(pA[s], lds + ldsA + (s << 10));
#pragma unroll
  for (int s = 0; s < 4; ++s) gld16(pB[s], lds + ldsB + (s << 10));
#pragma unroll
  for (int s = 0; s < 4; ++s) gld16(pB[s] + 64, lds + 65536 + ldsB + (s << 10));
#pragma unroll
  for (int s = 0; s < 4; ++s) { pA[s] += 64; pB[s] += 128; }
  asm volatile("s_waitcnt vmcnt(4)" ::: "memory");   // A(0),B(0) landed
  BAR;
  RDA32(0, 0); RDB32(0, 0);    // av(MH0), bv(NH0) for first cluster

  for (int j = 0; j < NT; ++j) {
    const int buf  = (j & 1) << 16;
    const int obuf = buf ^ 65536;
    const bool stA = (j + 1 < NT);
    const bool stB = (j + 2 < NT);
    // p0: stage A(j+1)[0,1]; M(0,0); read bv(1)
    if (stA) { gld16(pA[0], lds + obuf + ldsA);
               gld16(pA[1], lds + obuf + ldsA + 1024); }
    MFMAQ32(0, 0);
    RDB32(buf, 1);
    BAR;
    // p1: stage A(j+1)[2,3]; M(0,1); read av(1)
    if (stA) { gld16(pA[2], lds + obuf + ldsA + 2048);
               gld16(pA[3], lds + obuf + ldsA + 3072); }
    MFMAQ32(0, 1);
    RDA32(buf, 1);
    BAR;
    // p2: stage B(j+2)[0,1] -> this buf (bv(0) consumed at M(0,0), regs only after);
    //     M(1,1)
    if (stB) { gld16(pB[0], lds + buf + ldsB);
               gld16(pB[1], lds + buf + ldsB + 1024); }
    MFMAQ32(1, 1);
    BAR;
    // p3: stage B(j+2)[2,3]; vmcnt(4)+BAR (A(j+1),B(j+1) landed);
    //     M(1,0); read av(0)',bv(0)' from next buf
    if (stB) { gld16(pB[2], lds + buf + ldsB + 2048);
               gld16(pB[3], lds + buf + ldsB + 3072); }
    if (j < NT - 2)       { asm volatile("s_waitcnt vmcnt(4)" ::: "memory"); }
    else if (j == NT - 2) { asm volatile("s_waitcnt vmcnt(0)" ::: "memory"); }
    BAR;
    MFMAQ32(1, 0);
    if (stA) { RDA32(obuf, 0); RDB32(obuf, 0); }
#pragma unroll
    for (int s = 0; s < 4; ++s) { pA[s] += 64; pB[s] += 64; }
  }

  // ---- epilogue: C = acc + bias ----
  // 32x32 C/D: col = lane&31, row = (reg&3) + 8*(reg>>2) + 4*(lane>>5)
#pragma unroll
  for (int mm = 0; mm < 4; ++mm) {
    const int rowb = brow + wr * 128 + mm * 32 + 4 * khalf;
#pragma unroll
    for (int nn = 0; nn < 2; ++nn) {
      const int col = bcol + wc * 64 + nn * 32 + r;
      const float b2 = bias[col];
#pragma unroll
      for (int reg = 0; reg < 16; ++reg) {
        const int row = rowb + (reg & 3) + 8 * (reg >> 2);
        C[(size_t)row * ldc + col] = acc[mm][nn][reg] + b2;
      }
    }
  }
}

// ---------- launch ----------
extern "C" void kernel_launch(void* const* d_in, const int* in_sizes, int n_in,
                              void* d_out, int out_size, void* d_ws, size_t ws_size,
                              hipStream_t stream) {
  const float* x  = (const float*)d_in[0];   // [8192][4096]
  const float* Wb = (const float*)d_in[1];   // [4096][4096]
  const float* bb = (const float*)d_in[2];   // [4096]
  const float* Wg = (const float*)d_in[3];   // [8][4096]
  const float* A  = (const float*)d_in[4];   // [8][16][4096] = [128][4096]
  const float* B  = (const float*)d_in[5];   // [8][4096][16]
  float* out = (float*)d_out;                // [8192][4096]

  char* ws = (char*)d_ws;
  u16*   Xaug = (u16*)ws;                                     // 8192 x 4224 bf16
  u16*   Waug = (u16*)(ws + 69206016);                        // 4096 x 4224 bf16
  u16*   a2   = (u16*)(ws + 69206016 + 34603008);             // 128 x 4096 bf16
  float* wsc  = (float*)(ws + 69206016 + 34603008 + 1048576); // 8192 x 8
  // split-K partials live in d_out (16 MB; fully overwritten by gemm8p afterwards)
  float* hp   = out;

  // 1) cast x -> Xaug base + gate weights (fused; x read once)
  cast_x_gate<<<2048, 256, 0, stream>>>(x, Wg, Xaug, wsc);

  // 2) other casts
  cast_strided<<<2048, 256, 0, stream>>>(Wb, Waug, 4096, 4096, 4224);
  cast_strided<<<512,  256, 0, stream>>>(A,  a2,   128,  4096, 4096);
  cast_b2<<<2048, 256, 0, stream>>>(B, Waug);

  // 3) LoRA down-proj, split-K x4 -> partials in d_out
  lora_down<<<dim3(64, 4), 256, 0, stream>>>(Xaug, a2, hp);

  // 4) reduce partials + gate-scale -> Xaug[:, 4096:]
  reduce_hw<<<4096, 256, 0, stream>>>(hp, wsc, Xaug);

  // 5) main fused GEMM: out = Xaug @ Waug^T + bias (256^2, 32x32x16, pipelined)
  gemm8p<<<512, 512, 0, stream>>>(Xaug, Waug, bb, out, 4224, 4224, 4096, 4224);
}

// Round 7
// 396.524 us; speedup vs baseline: 1.0670x; 1.0670x over previous
//
#include <hip/hip_runtime.h>
#include <stdint.h>

typedef unsigned short u16;
typedef float f32x4 __attribute__((ext_vector_type(4)));
typedef short bf16x8 __attribute__((ext_vector_type(8)));

// ---------- helpers ----------
static __device__ __forceinline__ u16 f2bf(float f) {
  union { float f; unsigned u; } a; a.f = f;
  unsigned r = a.u + 0x7fffu + ((a.u >> 16) & 1u);   // round-nearest-even
  return (u16)(r >> 16);
}

static __device__ __forceinline__ void gld16(const void* g, void* l) {
  __builtin_amdgcn_global_load_lds(
      (const __attribute__((address_space(1))) void*)(uintptr_t)g,
      (__attribute__((address_space(3))) void*)(uintptr_t)l,
      16, 0, 0);
}

// ---------- fused weight cast: Waug[o][0:4096]=bf16(Wb), Waug[o][4096+er]=bf16(B*2) ----------
__global__ __launch_bounds__(256) void cast_w(
    const float* __restrict__ Wb, const float* __restrict__ B,
    u16* __restrict__ Waug) {
  const int total = 4096 * 1056;               // vec4 groups per full Waug
  for (int v = blockIdx.x * 256 + threadIdx.x; v < total;
       v += gridDim.x * 256) {
    const int o = v / 1056;
    const int cv = v - o * 1056;
    const int c = cv * 4;
    ushort4 out;
    if (c < 4096) {
      float4 w = *(const float4*)(Wb + (size_t)o * 4096 + c);
      out.x = f2bf(w.x); out.y = f2bf(w.y); out.z = f2bf(w.z); out.w = f2bf(w.w);
    } else {
      const int er = c - 4096;                 // multiple of 4
      const int e = er >> 4;
      const int r = er & 15;
      const float* bp = B + ((size_t)e * 4096 + o) * 16 + r;
      out.x = f2bf(bp[0] * 2.0f); out.y = f2bf(bp[1] * 2.0f);
      out.z = f2bf(bp[2] * 2.0f); out.w = f2bf(bp[3] * 2.0f);
    }
    *(ushort4*)(Waug + (size_t)o * 4224 + c) = out;
  }
}

// ---------- cast fp32 [rows][cols] -> bf16 [rows][ldd] (for A) ----------
__global__ __launch_bounds__(256) void cast_strided(
    const float* __restrict__ src, u16* __restrict__ dst,
    int rows, int cols, int ldd) {
  const size_t total = (size_t)rows * cols / 4;
  for (size_t i = (size_t)blockIdx.x * 256 + threadIdx.x; i < total;
       i += (size_t)gridDim.x * 256) {
    const size_t e = i * 4;
    const int r = (int)(e / cols);
    const int c = (int)(e % cols);
    float4 v = *(const float4*)(src + e);
    ushort4 o;
    o.x = f2bf(v.x); o.y = f2bf(v.y); o.z = f2bf(v.z); o.w = f2bf(v.w);
    *(ushort4*)(dst + (size_t)r * ldd + c) = o;
  }
}

// ---------- fused: cast x -> Xaug base cols AND compute gate weights ----------
__global__ __launch_bounds__(256) void cast_x_gate(
    const float* __restrict__ x, const float* __restrict__ Wg,
    u16* __restrict__ Xaug, float* __restrict__ wsc) {
  const int lane = threadIdx.x & 63;
  const int wv = threadIdx.x >> 6;
  const int n = blockIdx.x * 4 + wv;
  const float4* x4 = (const float4*)(x + (size_t)n * 4096);
  const float4* g4 = (const float4*)Wg;                  // [8][1024] float4
  u16* xr = Xaug + (size_t)n * 4224;
  float acc[8] = {0, 0, 0, 0, 0, 0, 0, 0};
#pragma unroll
  for (int ii = 0; ii < 16; ++ii) {
    const int i = ii * 64 + lane;
    float4 xv = x4[i];
    ushort4 o;
    o.x = f2bf(xv.x); o.y = f2bf(xv.y); o.z = f2bf(xv.z); o.w = f2bf(xv.w);
    *(ushort4*)(xr + i * 4) = o;
#pragma unroll
    for (int e = 0; e < 8; ++e) {
      float4 w4 = g4[e * 1024 + i];
      acc[e] += xv.x * w4.x + xv.y * w4.y + xv.z * w4.z + xv.w * w4.w;
    }
  }
#pragma unroll
  for (int e = 0; e < 8; ++e) {
#pragma unroll
    for (int off = 32; off > 0; off >>= 1)
      acc[e] += __shfl_xor(acc[e], off);
  }
  int i1 = 0; float m1 = acc[0];
#pragma unroll
  for (int e = 1; e < 8; ++e) if (acc[e] > m1) { m1 = acc[e]; i1 = e; }
  int i2 = -1; float m2 = -3.4e38f;
#pragma unroll
  for (int e = 0; e < 8; ++e) if (e != i1 && acc[e] > m2) { m2 = acc[e]; i2 = e; }
  float w1 = 1.0f / (1.0f + expf(m2 - m1));   // p1/(p1+p2) after softmax+renorm
  float w2 = 1.0f - w1;
  if (lane < 8)
    wsc[(size_t)n * 8 + lane] = (lane == i1) ? w1 : ((lane == i2) ? w2 : 0.0f);
}

// ---------- LoRA down-proj, split-K x4 -> f32 partials in hp ----------
__global__ __launch_bounds__(256) void lora_down(
    const u16* __restrict__ Xa, const u16* __restrict__ A2,
    float* __restrict__ hp) {
  __shared__ u16 sA[128 * 64];
  __shared__ u16 sB[128 * 64];
  const int t = threadIdx.x;
  const int lane = t & 63;
  const int wr = t >> 7;
  const int wc = (t >> 6) & 1;
  const int l15 = lane & 15;
  const int lhi = lane >> 4;
  f32x4 acc[4][4] = {};

  const int brow = blockIdx.x * 128;
  const int kbase = blockIdx.y * 1024;
  const int srow = t >> 3;
  const int scol = (t & 7) * 8;
  const size_t a_src = (size_t)(brow + srow) * 4224 + scol + kbase;
  const size_t b_src = (size_t)srow * 4096 + scol + kbase;

  for (int k0 = 0; k0 < 1024; k0 += 64) {
#pragma unroll
    for (int c = 0; c < 4; ++c)
      gld16(Xa + a_src + (size_t)c * 32 * 4224 + k0,
            &sA[(c * 32 + srow) * 64 + scol]);
#pragma unroll
    for (int c = 0; c < 4; ++c)
      gld16(A2 + b_src + (size_t)c * 32 * 4096 + k0,
            &sB[(c * 32 + srow) * 64 + scol]);
    __syncthreads();
#pragma unroll
    for (int kk = 0; kk < 2; ++kk) {
      bf16x8 av[4], bv[4];
#pragma unroll
      for (int m = 0; m < 4; ++m)
        av[m] = *(const bf16x8*)&sA[(wr * 64 + m * 16 + l15) * 64 + kk * 32 + lhi * 8];
#pragma unroll
      for (int n = 0; n < 4; ++n)
        bv[n] = *(const bf16x8*)&sB[(wc * 64 + n * 16 + l15) * 64 + kk * 32 + lhi * 8];
#pragma unroll
      for (int m = 0; m < 4; ++m)
#pragma unroll
        for (int n = 0; n < 4; ++n)
          acc[m][n] = __builtin_amdgcn_mfma_f32_16x16x32_bf16(av[m], bv[n], acc[m][n], 0, 0, 0);
    }
    __syncthreads();
  }
  float* out = hp + (size_t)blockIdx.y * (8192 * 128);
#pragma unroll
  for (int m = 0; m < 4; ++m) {
    const int rbase = brow + wr * 64 + m * 16 + lhi * 4;
#pragma unroll
    for (int n = 0; n < 4; ++n) {
      const int col = wc * 64 + n * 16 + l15;   // 0..127
#pragma unroll
      for (int j = 0; j < 4; ++j)
        out[(size_t)(rbase + j) * 128 + col] = acc[m][n][j];
    }
  }
}

// ---------- reduce split-K partials, apply gate weight, store bf16 to Xaug ----------
__global__ __launch_bounds__(256) void reduce_hw(
    const float* __restrict__ hp, const float* __restrict__ wsc,
    u16* __restrict__ Xaug) {
  int i = blockIdx.x * 256 + threadIdx.x;
  if (i >= 8192 * 128) return;
  const int n = i >> 7;
  const int er = i & 127;
  const int e = er >> 4;
  float v = hp[i] + hp[i + 1048576] + hp[i + 2097152] + hp[i + 3145728];
  Xaug[(size_t)n * 4224 + 4096 + er] = f2bf(v * wsc[n * 8 + e]);
}

// ================== 256x256 main GEMM: 16x16x32, ONE barrier per K-tile ==================
// BM=BN=256, BK=64, 512 thr (8 waves 2x4), per-wave 128x64 out (verified r5 frag paths).
// LDS 160KB: A double-buffered (2x32KB at 0/32768), B TRIPLE-buffered (3x32KB at
// 65536/98304/131072).  st_16x32 XOR swizzle via pre-swizzled global source (m173).
// Tile j: stage A(j+1)->bufA[(j+1)&1], B(j+2)->bufB[(j+2)%3] -- NEITHER is read in
// tile j, so there are NO intra-tile WAR hazards and no intra-tile barriers.
// One tile-end vmcnt(4)+s_barrier: A(j+1) landed (4 youngest = B(j+2) in flight);
// B(j+1) was issued a tile earlier (FIFO-older) => landed too.  vmcnt(0) only at tail.
#define BAR do { asm volatile("" ::: "memory"); __builtin_amdgcn_s_barrier(); asm volatile("" ::: "memory"); } while (0)

#define RDA(BUF, MH)                                                            \
  { _Pragma("unroll") for (int mm = 0; mm < 4; ++mm)                            \
    _Pragma("unroll") for (int kk = 0; kk < 2; ++kk)                            \
      av[mm][kk] = *(const bf16x8*)(lds + (BUF) + fbA + ((((MH) * 4 + mm) * 2 + kk) << 10)); }

#define RDB(BUF, NH)                                                            \
  { _Pragma("unroll") for (int nn = 0; nn < 2; ++nn)                            \
    _Pragma("unroll") for (int kk = 0; kk < 2; ++kk)                            \
      bv[(NH) * 2 + nn][kk] = *(const bf16x8*)(lds + (BUF) + fbB + ((((NH) * 2 + nn) * 2 + kk) << 10)); }

#define MFMAQ(MH, NH)                                                           \
  { __builtin_amdgcn_s_setprio(1);                                              \
    _Pragma("unroll") for (int kk = 0; kk < 2; ++kk)                            \
    _Pragma("unroll") for (int mm = 0; mm < 4; ++mm)                            \
    _Pragma("unroll") for (int nn = 0; nn < 2; ++nn)                            \
      acc[(MH) * 4 + mm][(NH) * 2 + nn] = __builtin_amdgcn_mfma_f32_16x16x32_bf16( \
          av[mm][kk], bv[(NH) * 2 + nn][kk], acc[(MH) * 4 + mm][(NH) * 2 + nn], 0, 0, 0); \
    __builtin_amdgcn_s_setprio(0); }

__global__ __launch_bounds__(512, 2) void gemm8p(
    const u16* __restrict__ Ag, const u16* __restrict__ Bg,
    const float* __restrict__ bias, float* __restrict__ C,
    int lda, int ldb, int ldc, int K) {
  __shared__ __align__(1024) char lds[163840];
  const int t = threadIdx.x;
  const int lane = t & 63;
  const int w = t >> 6;
  const int wr = w >> 2, wc = w & 3;
  const int l15 = lane & 15, lhi = lane >> 4;

  // XCD-slab mapping (verified r6: FETCH 304->203MB): xcd owns 4 consecutive tile_m;
  // concurrent 4-block groups share one B-panel in L2.
  const int bid = blockIdx.x;
  const int g = bid >> 3;
  const int tile_m = (bid & 7) * 4 + (g & 3);
  const int tile_n = g >> 2;
  const int brow = tile_m << 8;
  const int bcol = tile_n << 8;

  // pre-swizzled per-lane source coords (st_16x32 involution)
  const int sb = (lane << 4) ^ (lane & 32);
  const int srow = sb >> 6;
  const int scol = (sb & 63) >> 1;

  // wave w stages A subtiles w*4..w*4+3 and B subtiles w*4..w*4+3 per K-tile
  const u16* pA[4]; const u16* pB[4];
#pragma unroll
  for (int s = 0; s < 4; ++s) {
    const int idx = w * 4 + s;
    const int rg = idx >> 1, cs = idx & 1;
    pA[s] = Ag + (size_t)(brow + rg * 16 + srow) * lda + cs * 32 + scol;
    pB[s] = Bg + (size_t)(bcol + rg * 16 + srow) * ldb + cs * 32 + scol;
  }
  const int ldsW = w << 12;   // wave's 4KB staging slot within a 32KB buffer

  // fragment read bases (swizzled read of linear-written LDS; verified r3-r5)
  const int innerL = ((l15 << 6) + (lhi << 4)) ^ ((l15 & 8) << 2);
  const int fbA = (wr << 14) + innerL;
  const int fbB = (wc << 13) + innerL;

  f32x4 acc[8][4] = {};
  bf16x8 av[4][2], bv[4][2];

  const int NT = K >> 6;   // 66 K-tiles

  // ---- prologue: A(0)->A0, B(0)->B0, A(1)->A1, B(1)->B1, B(2)->B2 (FIFO order) ----
#pragma unroll
  for (int s = 0; s < 4; ++s) gld16(pA[s],       lds + (s << 10) + ldsW);            // A0
#pragma unroll
  for (int s = 0; s < 4; ++s) gld16(pB[s],       lds + 65536 + (s << 10) + ldsW);    // B0
#pragma unroll
  for (int s = 0; s < 4; ++s) gld16(pA[s] + 64,  lds + 32768 + (s << 10) + ldsW);    // A1
#pragma unroll
  for (int s = 0; s < 4; ++s) gld16(pB[s] + 64,  lds + 98304 + (s << 10) + ldsW);    // B1
#pragma unroll
  for (int s = 0; s < 4; ++s) gld16(pB[s] + 128, lds + 131072 + (s << 10) + ldsW);   // B2
  // in-loop staging for tile j (j>=1) reads pA at k=64*(j+1), pB at k=64*(j+2):
#pragma unroll
  for (int s = 0; s < 4; ++s) { pA[s] += 64; pB[s] += 128; }
  asm volatile("s_waitcnt vmcnt(12)" ::: "memory");   // A0,B0 landed
  BAR;

  int bA = 0;        // A buffer byte base for tile j: 0 / 32768
  int bB = 65536;    // B buffer byte base for tile j: 65536 + (j%3)*32768
  int bB2 = 131072;  // staging target for B(j+2)

  for (int j = 0; j < NT; ++j) {
    const int obA = bA ^ 32768;
    const bool stA = (j >= 1) & (j + 1 < NT);
    const bool stB = (j >= 1) & (j + 2 < NT);
    // tile-top reads for first cluster
    RDA(bA, 0); RDB(bB, 0);
    // stage next tiles (no intra-tile hazard: targets not read this tile)
    if (stA) {
#pragma unroll
      for (int s = 0; s < 4; ++s) gld16(pA[s], lds + obA + (s << 10) + ldsW);
    }
    if (stB) {
#pragma unroll
      for (int s = 0; s < 4; ++s) gld16(pB[s], lds + bB2 + (s << 10) + ldsW);
    }
    // clusters, reads pipelined one ahead (r5 pattern)
    MFMAQ(0, 0);
    RDB(bB, 1);
    MFMAQ(0, 1);
    RDA(bA, 1);
    MFMAQ(1, 1);
    MFMAQ(1, 0);
    // tile-end: counted drain + single barrier
    if (j < NT - 2)       { asm volatile("s_waitcnt vmcnt(4)" ::: "memory"); BAR; }
    else if (j == NT - 2) { asm volatile("s_waitcnt vmcnt(0)" ::: "memory"); BAR; }
    // rotate buffers / advance pointers
    bA = obA;
    bB = (bB == 131072) ? 65536 : bB + 32768;
    bB2 = (bB2 == 131072) ? 65536 : bB2 + 32768;
#pragma unroll
    for (int s = 0; s < 4; ++s) { pA[s] += 64; pB[s] += 64; }
  }

  // ---- epilogue: C = acc + bias (16x16 C/D: col=lane&15, row=(lane>>4)*4+j) ----
#pragma unroll
  for (int m = 0; m < 8; ++m) {
    const int row0 = brow + wr * 128 + m * 16 + lhi * 4;
#pragma unroll
    for (int n = 0; n < 4; ++n) {
      const int col = bcol + wc * 64 + n * 16 + l15;
      const float b2 = bias[col];
#pragma unroll
      for (int jj = 0; jj < 4; ++jj)
        C[(size_t)(row0 + jj) * ldc + col] = acc[m][n][jj] + b2;
    }
  }
}

// ---------- launch ----------
extern "C" void kernel_launch(void* const* d_in, const int* in_sizes, int n_in,
                              void* d_out, int out_size, void* d_ws, size_t ws_size,
                              hipStream_t stream) {
  const float* x  = (const float*)d_in[0];   // [8192][4096]
  const float* Wb = (const float*)d_in[1];   // [4096][4096]
  const float* bb = (const float*)d_in[2];   // [4096]
  const float* Wg = (const float*)d_in[3];   // [8][4096]
  const float* A  = (const float*)d_in[4];   // [8][16][4096] = [128][4096]
  const float* B  = (const float*)d_in[5];   // [8][4096][16]
  float* out = (float*)d_out;                // [8192][4096]

  char* ws = (char*)d_ws;
  u16*   Xaug = (u16*)ws;                                     // 8192 x 4224 bf16
  u16*   Waug = (u16*)(ws + 69206016);                        // 4096 x 4224 bf16
  u16*   a2   = (u16*)(ws + 69206016 + 34603008);             // 128 x 4096 bf16
  float* wsc  = (float*)(ws + 69206016 + 34603008 + 1048576); // 8192 x 8
  // split-K partials live in d_out (16 MB; fully overwritten by gemm8p afterwards)
  float* hp   = out;

  // 1) cast x -> Xaug base + gate weights (fused; x read once)
  cast_x_gate<<<2048, 256, 0, stream>>>(x, Wg, Xaug, wsc);

  // 2) weight casts (Wb + B fused into Waug; A separate)
  cast_w<<<2048, 256, 0, stream>>>(Wb, B, Waug);
  cast_strided<<<512, 256, 0, stream>>>(A, a2, 128, 4096, 4096);

  // 3) LoRA down-proj, split-K x4 -> partials in d_out
  lora_down<<<dim3(64, 4), 256, 0, stream>>>(Xaug, a2, hp);

  // 4) reduce partials + gate-scale -> Xaug[:, 4096:]
  reduce_hw<<<4096, 256, 0, stream>>>(hp, wsc, Xaug);

  // 5) main fused GEMM: out = Xaug @ Waug^T + bias (256^2, 1-barrier/K-tile)
  gemm8p<<<512, 512, 0, stream>>>(Xaug, Waug, bb, out, 4224, 4224, 4096, 4224);
}

// Round 8
// 385.377 us; speedup vs baseline: 1.0979x; 1.0289x over previous
//
#include <hip/hip_runtime.h>
#include <stdint.h>

typedef unsigned short u16;
typedef float f32x4 __attribute__((ext_vector_type(4)));
typedef short bf16x8 __attribute__((ext_vector_type(8)));

// ---------- helpers ----------
static __device__ __forceinline__ u16 f2bf(float f) {
  union { float f; unsigned u; } a; a.f = f;
  unsigned r = a.u + 0x7fffu + ((a.u >> 16) & 1u);   // round-nearest-even
  return (u16)(r >> 16);
}

static __device__ __forceinline__ void gld16(const void* g, void* l) {
  __builtin_amdgcn_global_load_lds(
      (const __attribute__((address_space(1))) void*)(uintptr_t)g,
      (__attribute__((address_space(3))) void*)(uintptr_t)l,
      16, 0, 0);
}

// ================== fused pre-pass: all casts + gating in ONE dispatch ==================
// bid <  2048 : cast x -> Xaug[:, :4096] bf16 AND gate weights wsc (1 wave/token)
// 2048..4095  : cast Wb -> Waug[:, :4096], B*SCALING -> Waug[:, 4096:] (grid-stride)
// 4096..4607  : cast A [128][4096] -> a2 bf16
__global__ __launch_bounds__(256) void fused_pre(
    const float* __restrict__ x, const float* __restrict__ Wg,
    const float* __restrict__ Wb, const float* __restrict__ B,
    const float* __restrict__ A,
    u16* __restrict__ Xaug, u16* __restrict__ Waug, u16* __restrict__ a2,
    float* __restrict__ wsc) {
  const int bid = blockIdx.x;
  const int t = threadIdx.x;
  if (bid < 2048) {
    // ---- cast x + gate ----
    const int lane = t & 63;
    const int wv = t >> 6;
    const int n = bid * 4 + wv;
    const float4* x4 = (const float4*)(x + (size_t)n * 4096);
    const float4* g4 = (const float4*)Wg;                  // [8][1024] float4
    u16* xr = Xaug + (size_t)n * 4224;
    float acc[8] = {0, 0, 0, 0, 0, 0, 0, 0};
#pragma unroll
    for (int ii = 0; ii < 16; ++ii) {
      const int i = ii * 64 + lane;
      float4 xv = x4[i];
      ushort4 o;
      o.x = f2bf(xv.x); o.y = f2bf(xv.y); o.z = f2bf(xv.z); o.w = f2bf(xv.w);
      *(ushort4*)(xr + i * 4) = o;
#pragma unroll
      for (int e = 0; e < 8; ++e) {
        float4 w4 = g4[e * 1024 + i];
        acc[e] += xv.x * w4.x + xv.y * w4.y + xv.z * w4.z + xv.w * w4.w;
      }
    }
#pragma unroll
    for (int e = 0; e < 8; ++e) {
#pragma unroll
      for (int off = 32; off > 0; off >>= 1)
        acc[e] += __shfl_xor(acc[e], off);
    }
    int i1 = 0; float m1 = acc[0];
#pragma unroll
    for (int e = 1; e < 8; ++e) if (acc[e] > m1) { m1 = acc[e]; i1 = e; }
    int i2 = -1; float m2 = -3.4e38f;
#pragma unroll
    for (int e = 0; e < 8; ++e) if (e != i1 && acc[e] > m2) { m2 = acc[e]; i2 = e; }
    float w1 = 1.0f / (1.0f + expf(m2 - m1));   // p1/(p1+p2) after softmax+renorm
    float w2 = 1.0f - w1;
    if (lane < 8)
      wsc[(size_t)n * 8 + lane] = (lane == i1) ? w1 : ((lane == i2) ? w2 : 0.0f);
  } else if (bid < 4096) {
    // ---- cast Wb + B -> Waug ----
    const int total = 4096 * 1056;               // vec4 groups
    for (int v = (bid - 2048) * 256 + t; v < total; v += 2048 * 256) {
      const int o = v / 1056;
      const int c = (v - o * 1056) * 4;
      ushort4 out;
      if (c < 4096) {
        float4 w = *(const float4*)(Wb + (size_t)o * 4096 + c);
        out.x = f2bf(w.x); out.y = f2bf(w.y); out.z = f2bf(w.z); out.w = f2bf(w.w);
      } else {
        const int er = c - 4096;
        const int e = er >> 4;
        const int r = er & 15;
        const float* bp = B + ((size_t)e * 4096 + o) * 16 + r;
        out.x = f2bf(bp[0] * 2.0f); out.y = f2bf(bp[1] * 2.0f);
        out.z = f2bf(bp[2] * 2.0f); out.w = f2bf(bp[3] * 2.0f);
      }
      *(ushort4*)(Waug + (size_t)o * 4224 + c) = out;
    }
  } else {
    // ---- cast A -> a2 ----
    const int i = (bid - 4096) * 256 + t;        // 0..131071 vec4 groups
    const size_t e = (size_t)i * 4;
    float4 v = *(const float4*)(A + e);
    ushort4 o;
    o.x = f2bf(v.x); o.y = f2bf(v.y); o.z = f2bf(v.z); o.w = f2bf(v.w);
    *(ushort4*)(a2 + e) = o;
  }
}

// ================== direct LoRA down-proj + gate-scale (no split-K) ==================
// Per block: 32 token-rows x all 128 (e,r) cols, K=4096.  grid=256 (1 block/CU).
// LDS 20KB: sA 32x64 (4 subtiles) + sB 128x64 (16 subtiles), st_16x32 involution:
// gld16 with uniform dest base (linear by lane) + pre-swizzled per-lane SOURCE;
// reads use the swizzled innerL -> conflict-free ds_read_b128 (verified gemm8p math).
__global__ __launch_bounds__(256) void lora_hw(
    const u16* __restrict__ Xa, const u16* __restrict__ A2,
    const float* __restrict__ wsc, u16* __restrict__ Xaug) {
  __shared__ __align__(1024) char lds[20480];
  const int t = threadIdx.x;
  const int lane = t & 63;
  const int w = t >> 6;               // 0..3, wave's 32-col strip
  const int l15 = lane & 15, lhi = lane >> 4;
  const int brow = blockIdx.x * 32;

  // pre-swizzled per-lane source coords (st_16x32 involution)
  const int sb = (lane << 4) ^ (lane & 32);
  const int srow = sb >> 6;
  const int scol = (sb & 63) >> 1;

  // staging: wave w -> A subtile w (rg=w>>1, cs=w&1); B subtiles w*4..w*4+3
  const u16* pA = Xa + (size_t)(brow + (w >> 1) * 16 + srow) * 4224 + (w & 1) * 32 + scol;
  const u16* pB[4];
#pragma unroll
  for (int s = 0; s < 4; ++s) {
    const int idx = w * 4 + s;
    pB[s] = A2 + (size_t)((idx >> 1) * 16 + srow) * 4096 + (idx & 1) * 32 + scol;
  }
  const int dA = w << 10;
  const int dB = 4096 + (w << 12);

  // swizzled fragment read base
  const int innerL = ((l15 << 6) + (lhi << 4)) ^ ((l15 & 8) << 2);

  f32x4 acc[2][2] = {};

  for (int k0 = 0; k0 < 4096; k0 += 64) {
    gld16(pA + k0, lds + dA);
#pragma unroll
    for (int s = 0; s < 4; ++s) gld16(pB[s] + k0, lds + dB + (s << 10));
    __syncthreads();
    bf16x8 av[2][2], bv[2][2];
#pragma unroll
    for (int m = 0; m < 2; ++m)
#pragma unroll
      for (int kk = 0; kk < 2; ++kk)
        av[m][kk] = *(const bf16x8*)(lds + ((m * 2 + kk) << 10) + innerL);
#pragma unroll
    for (int n = 0; n < 2; ++n)
#pragma unroll
      for (int kk = 0; kk < 2; ++kk)
        bv[n][kk] = *(const bf16x8*)(lds + 4096 + (((w * 2 + n) * 2 + kk) << 10) + innerL);
#pragma unroll
    for (int kk = 0; kk < 2; ++kk)
#pragma unroll
      for (int m = 0; m < 2; ++m)
#pragma unroll
        for (int n = 0; n < 2; ++n)
          acc[m][n] = __builtin_amdgcn_mfma_f32_16x16x32_bf16(av[m][kk], bv[n][kk], acc[m][n], 0, 0, 0);
    __syncthreads();
  }
  // epilogue: row = brow + m*16 + lhi*4 + j, col = w*32 + n*16 + l15 (0..127)
#pragma unroll
  for (int m = 0; m < 2; ++m) {
    const int rbase = brow + m * 16 + lhi * 4;
#pragma unroll
    for (int n = 0; n < 2; ++n) {
      const int col = w * 32 + n * 16 + l15;
#pragma unroll
      for (int j = 0; j < 4; ++j) {
        const int row = rbase + j;
        const float g = wsc[(size_t)row * 8 + (col >> 4)];
        Xaug[(size_t)row * 4224 + 4096 + col] = f2bf(acc[m][n][j] * g);
      }
    }
  }
}

// ================== 256x256 main GEMM (r5 schedule + XCD-slab mapping) ==================
// BM=BN=256, BK=64, 512 thr (8 waves 2x4), per-wave 128x64 out.
// LDS: 2 bufs x (A 32KB + B 32KB), st_16x32 swizzle via pre-swizzled global src.
// r5 pipelined-read schedule (best measured: 239.9us): reads trail previous MFMA
// cluster; 4 barriers/K-tile; staging 2 gld16/phase; counted vmcnt(4) (0 only tail).
// Block mapping: XCD-slab (r6/r7 verified FETCH 304->203MB).
#define BAR do { asm volatile("" ::: "memory"); __builtin_amdgcn_s_barrier(); asm volatile("" ::: "memory"); } while (0)

#define RDA(BUF, MH)                                                            \
  { _Pragma("unroll") for (int mm = 0; mm < 4; ++mm)                            \
    _Pragma("unroll") for (int kk = 0; kk < 2; ++kk)                            \
      av[mm][kk] = *(const bf16x8*)(lds + (BUF) + fbA + ((((MH) * 4 + mm) * 2 + kk) << 10)); }

#define RDB(BUF, NH)                                                            \
  { _Pragma("unroll") for (int nn = 0; nn < 2; ++nn)                            \
    _Pragma("unroll") for (int kk = 0; kk < 2; ++kk)                            \
      bv[(NH) * 2 + nn][kk] = *(const bf16x8*)(lds + (BUF) + fbB + ((((NH) * 2 + nn) * 2 + kk) << 10)); }

#define MFMAQ(MH, NH)                                                           \
  { __builtin_amdgcn_s_setprio(1);                                              \
    _Pragma("unroll") for (int kk = 0; kk < 2; ++kk)                            \
    _Pragma("unroll") for (int mm = 0; mm < 4; ++mm)                            \
    _Pragma("unroll") for (int nn = 0; nn < 2; ++nn)                            \
      acc[(MH) * 4 + mm][(NH) * 2 + nn] = __builtin_amdgcn_mfma_f32_16x16x32_bf16( \
          av[mm][kk], bv[(NH) * 2 + nn][kk], acc[(MH) * 4 + mm][(NH) * 2 + nn], 0, 0, 0); \
    __builtin_amdgcn_s_setprio(0); }

__global__ __launch_bounds__(512, 2) void gemm8p(
    const u16* __restrict__ Ag, const u16* __restrict__ Bg,
    const float* __restrict__ bias, float* __restrict__ C,
    int lda, int ldb, int ldc, int K) {
  __shared__ __align__(1024) char lds[131072];
  const int t = threadIdx.x;
  const int lane = t & 63;
  const int w = t >> 6;
  const int wr = w >> 2, wc = w & 3;
  const int l15 = lane & 15, lhi = lane >> 4;

  // XCD-slab mapping: xcd owns 4 consecutive tile_m; concurrent 4-block groups
  // share one B-panel in L2; A-panels hit HBM exactly once.
  const int bid = blockIdx.x;
  const int g = bid >> 3;
  const int tile_m = (bid & 7) * 4 + (g & 3);
  const int tile_n = g >> 2;
  const int brow = tile_m << 8;
  const int bcol = tile_n << 8;

  // pre-swizzled per-lane source coords (st_16x32 involution)
  const int sb = (lane << 4) ^ (lane & 32);
  const int srow = sb >> 6;
  const int scol = (sb & 63) >> 1;

  // wave w stages A subtiles w*4..w*4+3 and B subtiles w*4..w*4+3 per K-tile
  const u16* pA[4]; const u16* pB[4];
#pragma unroll
  for (int s = 0; s < 4; ++s) {
    const int idx = w * 4 + s;
    const int rg = idx >> 1, cs = idx & 1;
    pA[s] = Ag + (size_t)(brow + rg * 16 + srow) * lda + cs * 32 + scol;
    pB[s] = Bg + (size_t)(bcol + rg * 16 + srow) * ldb + cs * 32 + scol;
  }
  const int ldsA = w << 12;
  const int ldsB = 32768 + (w << 12);

  // fragment read bases (swizzled read of linear-written LDS)
  const int innerL = ((l15 << 6) + (lhi << 4)) ^ ((l15 & 8) << 2);
  const int fbA = (wr << 14) + innerL;
  const int fbB = 32768 + (wc << 13) + innerL;

  f32x4 acc[8][4] = {};
  bf16x8 av[4][2], bv[4][2];

  const int NT = K >> 6;   // 66 K-tiles

  // ---- prologue: stage A(0)->buf0, B(0)->buf0, B(1)->buf1 ----
#pragma unroll
  for (int s = 0; s < 4; ++s) gld16(pA[s], lds + ldsA + (s << 10));
#pragma unroll
  for (int s = 0; s < 4; ++s) gld16(pB[s], lds + ldsB + (s << 10));
#pragma unroll
  for (int s = 0; s < 4; ++s) gld16(pB[s] + 64, lds + 65536 + ldsB + (s << 10));
#pragma unroll
  for (int s = 0; s < 4; ++s) { pA[s] += 64; pB[s] += 128; }
  asm volatile("s_waitcnt vmcnt(4)" ::: "memory");   // A(0),B(0) landed
  BAR;
  RDA(0, 0); RDB(0, 0);    // av0(0), bv01(0) for first M0

  for (int j = 0; j < NT; ++j) {
    const int buf  = (j & 1) << 16;
    const int obuf = buf ^ 65536;
    const bool stA = (j + 1 < NT);
    const bool stB = (j + 2 < NT);
    // p0: stage A(j+1)[0,1]; M0 [av0,bv01]; read bv23 (regs free)
    if (stA) { gld16(pA[0], lds + obuf + ldsA);
               gld16(pA[1], lds + obuf + ldsA + 1024); }
    MFMAQ(0, 0);
    RDB(buf, 1);
    BAR;
    // p1: stage A(j+1)[2,3]; M1 [av0,bv23]; read av1 (av regs die at M1 issue)
    if (stA) { gld16(pA[2], lds + obuf + ldsA + 2048);
               gld16(pA[3], lds + obuf + ldsA + 3072); }
    MFMAQ(0, 1);
    RDA(buf, 1);
    BAR;
    // p2: stage B(j+2)[0,1] -> this buf (bv01(j) consumed at M0, bv23 at M1); M2
    if (stB) { gld16(pB[0], lds + buf + ldsB);
               gld16(pB[1], lds + buf + ldsB + 1024); }
    MFMAQ(1, 1);
    BAR;
    // p3: stage B(j+2)[2,3]; vmcnt(4)+BAR (A(j+1),B(j+1) landed);
    //     M3 [av1,bv01]; read av0',bv01' from next buf (regs die at M3 issue)
    if (stB) { gld16(pB[2], lds + buf + ldsB + 2048);
               gld16(pB[3], lds + buf + ldsB + 3072); }
    if (j < NT - 2)       { asm volatile("s_waitcnt vmcnt(4)" ::: "memory"); }
    else if (j == NT - 2) { asm volatile("s_waitcnt vmcnt(0)" ::: "memory"); }
    BAR;
    MFMAQ(1, 0);
    if (stA) { RDA(obuf, 0); RDB(obuf, 0); }
#pragma unroll
    for (int s = 0; s < 4; ++s) { pA[s] += 64; pB[s] += 64; }
  }

  // ---- epilogue: C = acc + bias ----
#pragma unroll
  for (int m = 0; m < 8; ++m) {
    const int row0 = brow + wr * 128 + m * 16 + lhi * 4;
#pragma unroll
    for (int n = 0; n < 4; ++n) {
      const int col = bcol + wc * 64 + n * 16 + l15;
      const float b2 = bias[col];
#pragma unroll
      for (int jj = 0; jj < 4; ++jj)
        C[(size_t)(row0 + jj) * ldc + col] = acc[m][n][jj] + b2;
    }
  }
}

// ---------- launch ----------
extern "C" void kernel_launch(void* const* d_in, const int* in_sizes, int n_in,
                              void* d_out, int out_size, void* d_ws, size_t ws_size,
                              hipStream_t stream) {
  const float* x  = (const float*)d_in[0];   // [8192][4096]
  const float* Wb = (const float*)d_in[1];   // [4096][4096]
  const float* bb = (const float*)d_in[2];   // [4096]
  const float* Wg = (const float*)d_in[3];   // [8][4096]
  const float* A  = (const float*)d_in[4];   // [8][16][4096] = [128][4096]
  const float* B  = (const float*)d_in[5];   // [8][4096][16]
  float* out = (float*)d_out;                // [8192][4096]

  char* ws = (char*)d_ws;
  u16*   Xaug = (u16*)ws;                                     // 8192 x 4224 bf16
  u16*   Waug = (u16*)(ws + 69206016);                        // 4096 x 4224 bf16
  u16*   a2   = (u16*)(ws + 69206016 + 34603008);             // 128 x 4096 bf16
  float* wsc  = (float*)(ws + 69206016 + 34603008 + 1048576); // 8192 x 8

  // 1) ALL casts + gating in one dispatch
  fused_pre<<<4608, 256, 0, stream>>>(x, Wg, Wb, B, A, Xaug, Waug, a2, wsc);

  // 2) LoRA down-proj + gate-scale -> Xaug[:, 4096:] (direct, conflict-free LDS)
  lora_hw<<<256, 256, 0, stream>>>(Xaug, a2, wsc, Xaug);

  // 3) main fused GEMM: out = Xaug @ Waug^T + bias
  gemm8p<<<512, 512, 0, stream>>>(Xaug, Waug, bb, out, 4224, 4224, 4096, 4224);
}